// Round 20
// baseline (801.131 us; speedup 1.0000x reference)
//
#include <hip/hip_runtime.h>
#include <hip/hip_bf16.h>

#define B_    16
#define FEA_  512
#define DM_   1024
#define HALF_ 512
#define DFF_  2048

typedef unsigned short u16;
typedef __attribute__((ext_vector_type(8))) short bf16x8;
typedef __attribute__((ext_vector_type(4))) float f32x4;

__device__ __forceinline__ float bf2f(u16 u) {
  union { unsigned int i; float f; } v; v.i = ((unsigned int)u) << 16; return v.f;
}
__device__ __forceinline__ u16 f2bf(float f) {
  union { float f; unsigned int i; } v; v.f = f;
  unsigned int x = v.i;
  return (u16)((x + 0x7fffu + ((x >> 16) & 1u)) >> 16);
}
__device__ __forceinline__ void gload16(const u16* g, u16* l) {
  __builtin_amdgcn_global_load_lds(
      (const __attribute__((address_space(1))) void*)g,
      (__attribute__((address_space(3))) void*)l, 16, 0, 0);
}

// ---------------- DWT (Haar, level 1, last axis), float4 ----------------
__global__ void dwt_kernel(const float* __restrict__ x, u16* __restrict__ x1,
                           u16* __restrict__ x2, int n2) {
  int i = blockIdx.x * 256 + threadIdx.x;
  if (i >= n2) return;
  float4 v = ((const float4*)x)[i];
  ushort2 a, d;
  a.x = f2bf((v.x + v.y) * 0.70710678118f);
  a.y = f2bf((v.z + v.w) * 0.70710678118f);
  d.x = f2bf((v.x - v.y) * 0.70710678118f);
  d.y = f2bf((v.z - v.w) * 0.70710678118f);
  ((ushort2*)x1)[i] = a;
  ((ushort2*)x2)[i] = d;
}

// ---------------- weight transpose, fused variants ----------------
__global__ void wtrans3_kernel(const float* __restrict__ w0, const float* __restrict__ w1,
                               const float* __restrict__ w2, u16* __restrict__ wt,
                               int Cout, int Cin) {
  int n = Cout * Cin * 3;
  int e = blockIdx.x * 256 + threadIdx.x;
  if (e >= 3 * n) return;
  int i = e / n, le = e - i * n;
  const float* w = (i == 0) ? w0 : ((i == 1) ? w1 : w2);
  int co = le / (Cin * 3);
  int r  = le - co * Cin * 3;
  int ci = r / 3;
  int t  = r - ci * 3;
  wt[(size_t)i * n + ((size_t)t * Cout + co) * Cin + ci] = f2bf(w[le]);
}

struct WTSeg { const float* src; u16* dst; int cout, cin, base; };
struct WT5 { WTSeg s[5]; int total; };
__global__ void wtrans5_kernel(WT5 p) {
  int e = blockIdx.x * 256 + threadIdx.x;
  if (e >= p.total) return;
#pragma unroll
  for (int i = 0; i < 5; ++i) {
    int Cin = p.s[i].cin, Cout = p.s[i].cout;
    int n = Cout * Cin * 3;
    int le = e - p.s[i].base;
    if (le >= 0 && le < n) {
      int co = le / (Cin * 3);
      int r  = le - co * Cin * 3;
      int ci = r / 3;
      int t  = r - ci * 3;
      p.s[i].dst[((size_t)t * Cout + co) * Cin + ci] = f2bf(p.s[i].src[le]);
    }
  }
}

// ---------------- circular conv1d (k=3) as MFMA GEMM (r20) ----------------
// 2-buffer Wb + issue-early/wait-vmcnt(0)-at-top (the attn-r17-proven
// discipline) -> LDS 49.4KB -> 3 blocks/CU (was 65.8KB / 2 blocks).
// Each W(k+1) is issued right after chunk k's top barrier => a full compute
// phase of landing time before its vmcnt(0) wait (unlike r11's drain).
// Buffer reuse distance: write targets the buffer last READ one chunk ago,
// separated by the top barrier. Boundary-Z choreography from r15 unchanged.
#define ZS_GLOAD(c0_)                                                        \
  {                                                                          \
    _Pragma("unroll") for (int i_ = 0; i_ < 5; ++i_) {                       \
      int e_ = tid + i_ * 256;                                               \
      if (e_ < 130 * 8) {                                                    \
        int r_ = e_ >> 3, c_ = e_ & 7;                                       \
        int gl_ = l0 + r_ - 1;                                               \
        if (gl_ < 0) gl_ += L; else if (gl_ >= L) gl_ -= L;                  \
        gload16(Zb + (size_t)gl_ * Cin + (c0_) + ((c_ ^ (r_ & 7)) * 8),      \
                smem + ((size_t)(i_ * 256 + (tid & 192)) * 8));              \
      }                                                                      \
    }                                                                        \
  }
#define WS_ISSUE(t_, c0_, buf_)                                              \
  {                                                                          \
    const u16* Wg_ = Wt + ((size_t)(t_) * Cout + co0) * Cin + (c0_);         \
    int c_ = lane & 7;                                                       \
    _Pragma("unroll") for (int i_ = 0; i_ < 4; ++i_) {                       \
      int rw_ = (i_ * 4 + w) * 8 + (lane >> 3);                              \
      gload16(Wg_ + (size_t)rw_ * Cin + ((c_ ^ (rw_ & 7)) * 8),              \
              &Wb[(buf_)][(i_ * 4 + w) * 8][0]);                             \
    }                                                                        \
  }
#define COMPUTE(t_, buf_)                                                    \
  {                                                                          \
    _Pragma("unroll") for (int ks = 0; ks < 2; ++ks) {                       \
      int s = ks * 4 + g4;                                                   \
      bf16x8 af[4], bfr[4];                                                  \
      _Pragma("unroll") for (int mi = 0; mi < 4; ++mi) {                     \
        int ra = wr * 64 + mi * 16 + row16 + (t_);                           \
        af[mi] = *(const bf16x8*)&Zs[ra][(s ^ (ra & 7)) * 8];                \
      }                                                                      \
      _Pragma("unroll") for (int ni = 0; ni < 4; ++ni) {                     \
        int rb = wc * 64 + ni * 16 + row16;                                  \
        bfr[ni] = *(const bf16x8*)&Wb[(buf_)][rb][(s ^ (rb & 7)) * 8];       \
      }                                                                      \
      __builtin_amdgcn_s_setprio(1);                                         \
      _Pragma("unroll") for (int mi = 0; mi < 4; ++mi)                       \
        _Pragma("unroll") for (int ni = 0; ni < 4; ++ni)                     \
          acc[mi][ni] = __builtin_amdgcn_mfma_f32_16x16x32_bf16(             \
              af[mi], bfr[ni], acc[mi][ni], 0, 0, 0);                        \
      __builtin_amdgcn_s_setprio(0);                                         \
    }                                                                        \
  }
#define COMPUTE2_REG(buf_)                                                   \
  {                                                                          \
    _Pragma("unroll") for (int ks = 0; ks < 2; ++ks) {                       \
      int s = ks * 4 + g4;                                                   \
      bf16x8 bfr[4];                                                         \
      _Pragma("unroll") for (int ni = 0; ni < 4; ++ni) {                     \
        int rb = wc * 64 + ni * 16 + row16;                                  \
        bfr[ni] = *(const bf16x8*)&Wb[(buf_)][rb][(s ^ (rb & 7)) * 8];       \
      }                                                                      \
      __builtin_amdgcn_s_setprio(1);                                         \
      _Pragma("unroll") for (int mi = 0; mi < 4; ++mi)                       \
        _Pragma("unroll") for (int ni = 0; ni < 4; ++ni)                     \
          acc[mi][ni] = __builtin_amdgcn_mfma_f32_16x16x32_bf16(             \
              af2[ks * 4 + mi], bfr[ni], acc[mi][ni], 0, 0, 0);              \
      __builtin_amdgcn_s_setprio(0);                                         \
    }                                                                        \
  }
#define WAITV0 { asm volatile("s_waitcnt vmcnt(0)" ::: "memory");            \
                 __builtin_amdgcn_s_barrier(); }

__global__ __launch_bounds__(256, 3) void conv_mfma_kernel(
    const u16* __restrict__ Z, const u16* __restrict__ Wt,
    const float* __restrict__ bias, u16* __restrict__ out,
    int L, int Cin, int Cout, int osl, int osc, int relu) {
  __shared__ __align__(16) u16 smem[130 * 64 + 2 * 128 * 64];
  u16 (*Zs)[64] = (u16(*)[64])smem;
  u16 (*Wb)[128][64] = (u16(*)[128][64])(smem + 130 * 64);
  int l0 = blockIdx.x * 128, co0 = blockIdx.y * 128, b = blockIdx.z;
  int tid = threadIdx.x;
  int lane = tid & 63, w = tid >> 6, wr = w >> 1, wc = w & 1;
  int row16 = lane & 15, g4 = lane >> 4;
  f32x4 acc[4][4];
#pragma unroll
  for (int i = 0; i < 4; ++i)
#pragma unroll
    for (int j = 0; j < 4; ++j) acc[i][j] = (f32x4){0.f, 0.f, 0.f, 0.f};
  const u16* Zb = Z + (size_t)b * L * Cin;

  int ncg = Cin >> 6;
  ZS_GLOAD(0);
  WS_ISSUE(0, 0, 0);      // chunk 0 -> buf 0
  int k = 0;

  for (int cg = 0; cg < ncg; ++cg) {
    int c0 = cg << 6;
    bool lastg = (cg == ncg - 1);
    // ---- chunk t=0 ----
    WAITV0;                                 // W(k) landed (1 phase in flight)
    WS_ISSUE(1, c0, (k + 1) & 1);
    COMPUTE(0, k & 1);
    ++k;
    // ---- chunk t=1 ----
    WAITV0;
    WS_ISSUE(2, c0, (k + 1) & 1);
    COMPUTE(1, k & 1);
    ++k;
    // ---- chunk t=2 ----
    WAITV0;
    if (!lastg) {
      WS_ISSUE(0, c0 + 64, (k + 1) & 1);
      bf16x8 af2[8];
#pragma unroll
      for (int ks = 0; ks < 2; ++ks) {
        int s = ks * 4 + g4;
#pragma unroll
        for (int mi = 0; mi < 4; ++mi) {
          int ra = wr * 64 + mi * 16 + row16 + 2;
          af2[ks * 4 + mi] = *(const bf16x8*)&Zs[ra][(s ^ (ra & 7)) * 8];
        }
      }
      __builtin_amdgcn_sched_barrier(0);
      asm volatile("s_waitcnt lgkmcnt(0)" ::: "memory");
      __builtin_amdgcn_s_barrier();         // all waves hold A-frags; Zs dead
      ZS_GLOAD(c0 + 64);                    // next group's Z, a phase early
      COMPUTE2_REG(k & 1);
    } else {
      COMPUTE(2, k & 1);
    }
    ++k;
  }

  // ---- coalesced epilogue: stage tile in LDS (row = strided dim) ----
  __syncthreads();
  const int TP = 136;
  u16* tile = smem;                         // 34.8KB <= 49.4KB pool
  size_t ob = (size_t)b * L * Cout;
  int S, rowbase, colbase;
  if (osc == 1) { S = osl; rowbase = l0; colbase = co0; }
  else          { S = osc; rowbase = co0; colbase = l0; }
#pragma unroll
  for (int ni = 0; ni < 4; ++ni) {
    int c_loc = wc * 64 + ni * 16 + row16;
    float bz = bias[co0 + c_loc];
#pragma unroll
    for (int mi = 0; mi < 4; ++mi) {
#pragma unroll
      for (int r = 0; r < 4; ++r) {
        int l_loc = wr * 64 + mi * 16 + g4 * 4 + r;
        float v = acc[mi][ni][r] + bz;
        if (relu) v = fmaxf(v, 0.f);
        int row = (osc == 1) ? l_loc : c_loc;
        int col = (osc == 1) ? c_loc : l_loc;
        tile[row * TP + col] = f2bf(v);
      }
    }
  }
  __syncthreads();
  for (int e = tid; e < 128 * 16; e += 256) {
    int row = e >> 4, c8 = (e & 15) * 8;
    *(uint4*)(out + ob + (size_t)(rowbase + row) * S + colbase + c8) =
        *(const uint4*)&tile[row * TP + c8];
  }
}

// ---------------- fused cross attention, MFMA, pipelined (r17, kept) ----------------
#define AQOFF 0
#define AKOFF 4096
#define AVOFF 12288
#define APOFF 20480
#define AT_Q_STAGE()                                                         \
  { _Pragma("unroll") for (int i_ = 0; i_ < 2; ++i_) {                       \
      int idx_ = tid + i_ * 256; int r_ = idx_ >> 3, c_ = idx_ & 7;          \
      gload16(Qg + (size_t)(q0 + r_) * DM_ + ((c_ ^ (r_ & 7)) * 8),          \
              asm_ + AQOFF + (i_ * 256 + (tid & 192)) * 8); } }
#define AT_K_STAGE(kt_, buf_)                                                \
  { _Pragma("unroll") for (int i_ = 0; i_ < 2; ++i_) {                       \
      int idx_ = tid + i_ * 256; int r_ = idx_ >> 3, c_ = idx_ & 7;          \
      gload16(Kg + (size_t)((kt_) * 64 + r_) * DM_ + ((c_ ^ (r_ & 7)) * 8),  \
              asm_ + AKOFF + (buf_) * 4096 + (i_ * 256 + (tid & 192)) * 8); } }
#define AT_V_STAGE(kt_, buf_)                                                \
  { _Pragma("unroll") for (int i_ = 0; i_ < 2; ++i_) {                       \
      int idx_ = tid + i_ * 256; int r_ = idx_ >> 3, c_ = idx_ & 7;          \
      gload16(Vg + (size_t)r_ * FEA_ + (kt_) * 64 + ((c_ ^ (r_ & 7)) * 8),   \
              asm_ + AVOFF + (buf_) * 4096 + (i_ * 256 + (tid & 192)) * 8); } }
#define LGKM0_BAR { asm volatile("s_waitcnt lgkmcnt(0)" ::: "memory");       \
                    __builtin_amdgcn_s_barrier(); }

__global__ __launch_bounds__(256, 3) void attn_mfma_kernel(
    const u16* __restrict__ qh, const u16* __restrict__ kh, const u16* __restrict__ vhT,
    const u16* __restrict__ ql, const u16* __restrict__ kl, const u16* __restrict__ vlT,
    u16* __restrict__ ctx) {
  __shared__ __align__(16) u16 asm_[24576];
  __shared__ float rsl[2][2][32];   // [wr][wc][q]
  int qt = blockIdx.x, h = blockIdx.y, bz = blockIdx.z;
  int b = bz >> 1, br = bz & 1;
  const u16* Qg = (br ? ql  : qh) + (size_t)b * FEA_ * DM_ + h * 64;
  const u16* Kg = (br ? kh  : kl) + (size_t)b * FEA_ * DM_ + h * 64;
  const u16* Vg = (br ? vlT : vhT) + (size_t)b * DM_ * FEA_ + (size_t)(h * 64) * FEA_;
  int tid = threadIdx.x;
  int lane = tid & 63, w = tid >> 6, wr = w >> 1, wc = w & 1;
  int row16 = lane & 15, g4 = lane >> 4;
  int q0 = qt * 64;

  f32x4 oacc[2][2];
  float rsum[2][4];
#pragma unroll
  for (int i = 0; i < 2; ++i) {
#pragma unroll
    for (int j = 0; j < 2; ++j) oacc[i][j] = (f32x4){0.f, 0.f, 0.f, 0.f};
#pragma unroll
    for (int r = 0; r < 4; ++r) rsum[i][r] = 0.f;
  }

  AT_Q_STAGE();
  AT_K_STAGE(0, 0); AT_V_STAGE(0, 0);

  for (int kt = 0; kt < 8; ++kt) {
    int buf = kt & 1;
    asm volatile("s_waitcnt vmcnt(0)" ::: "memory");
    __builtin_amdgcn_s_barrier();
    if (kt < 7) { AT_K_STAGE(kt + 1, buf ^ 1); AT_V_STAGE(kt + 1, buf ^ 1); }
    f32x4 sacc[2][2];
#pragma unroll
    for (int i = 0; i < 2; ++i)
#pragma unroll
      for (int j = 0; j < 2; ++j) sacc[i][j] = (f32x4){0.f, 0.f, 0.f, 0.f};
#pragma unroll
    for (int ks = 0; ks < 2; ++ks) {
      int s = ks * 4 + g4;
      bf16x8 a0, a1, b0, b1;
      { int ra = wr * 32 + row16;
        a0 = *(const bf16x8*)&asm_[AQOFF + ra * 64 + ((s ^ (ra & 7)) * 8)]; }
      { int ra = wr * 32 + 16 + row16;
        a1 = *(const bf16x8*)&asm_[AQOFF + ra * 64 + ((s ^ (ra & 7)) * 8)]; }
      { int rb = wc * 32 + row16;
        b0 = *(const bf16x8*)&asm_[AKOFF + buf * 4096 + rb * 64 + ((s ^ (rb & 7)) * 8)]; }
      { int rb = wc * 32 + 16 + row16;
        b1 = *(const bf16x8*)&asm_[AKOFF + buf * 4096 + rb * 64 + ((s ^ (rb & 7)) * 8)]; }
      __builtin_amdgcn_s_setprio(1);
      sacc[0][0] = __builtin_amdgcn_mfma_f32_16x16x32_bf16(a0, b0, sacc[0][0], 0, 0, 0);
      sacc[0][1] = __builtin_amdgcn_mfma_f32_16x16x32_bf16(a0, b1, sacc[0][1], 0, 0, 0);
      sacc[1][0] = __builtin_amdgcn_mfma_f32_16x16x32_bf16(a1, b0, sacc[1][0], 0, 0, 0);
      sacc[1][1] = __builtin_amdgcn_mfma_f32_16x16x32_bf16(a1, b1, sacc[1][1], 0, 0, 0);
      __builtin_amdgcn_s_setprio(0);
    }
#pragma unroll
    for (int mi = 0; mi < 2; ++mi)
#pragma unroll
      for (int ni = 0; ni < 2; ++ni)
#pragma unroll
        for (int r = 0; r < 4; ++r) {
          float p = __expf(sacc[mi][ni][r] * 0.25f);
          rsum[mi][r] += p;
          int pr = wr * 32 + mi * 16 + g4 * 4 + r;
          int ck = wc * 32 + ni * 16 + row16;
          asm_[APOFF + pr * 64 + (((ck >> 3) ^ (pr & 7)) * 8 + (ck & 7))] = f2bf(p);
        }
    LGKM0_BAR;                    // Ps published
#pragma unroll
    for (int ks = 0; ks < 2; ++ks) {
      int s = ks * 4 + g4;
      bf16x8 a0, a1, b0, b1;
      { int pa = wr * 32 + row16;
        a0 = *(const bf16x8*)&asm_[APOFF + pa * 64 + ((s ^ (pa & 7)) * 8)]; }
      { int pa = wr * 32 + 16 + row16;
        a1 = *(const bf16x8*)&asm_[APOFF + pa * 64 + ((s ^ (pa & 7)) * 8)]; }
      { int rv = wc * 32 + row16;
        b0 = *(const bf16x8*)&asm_[AVOFF + buf * 4096 + rv * 64 + ((s ^ (rv & 7)) * 8)]; }
      { int rv = wc * 32 + 16 + row16;
        b1 = *(const bf16x8*)&asm_[AVOFF + buf * 4096 + rv * 64 + ((s ^ (rv & 7)) * 8)]; }
      __builtin_amdgcn_s_setprio(1);
      oacc[0][0] = __builtin_amdgcn_mfma_f32_16x16x32_bf16(a0, b0, oacc[0][0], 0, 0, 0);
      oacc[0][1] = __builtin_amdgcn_mfma_f32_16x16x32_bf16(a0, b1, oacc[0][1], 0, 0, 0);
      oacc[1][0] = __builtin_amdgcn_mfma_f32_16x16x32_bf16(a1, b0, oacc[1][0], 0, 0, 0);
      oacc[1][1] = __builtin_amdgcn_mfma_f32_16x16x32_bf16(a1, b1, oacc[1][1], 0, 0, 0);
      __builtin_amdgcn_s_setprio(0);
    }
  }

  // ---- epilogue: denominators, O staging (reuse P area as Ot[d][q]), write ----
#pragma unroll
  for (int mi = 0; mi < 2; ++mi)
#pragma unroll
    for (int r = 0; r < 4; ++r) {
#pragma unroll
      for (int m = 1; m < 16; m <<= 1) rsum[mi][r] += __shfl_xor(rsum[mi][r], m);
    }
  if (row16 == 0) {
#pragma unroll
    for (int mi = 0; mi < 2; ++mi)
#pragma unroll
      for (int r = 0; r < 4; ++r) rsl[wr][wc][mi * 16 + g4 * 4 + r] = rsum[mi][r];
  }
  __syncthreads();
#pragma unroll
  for (int mi = 0; mi < 2; ++mi)
#pragma unroll
    for (int ni = 0; ni < 2; ++ni)
#pragma unroll
      for (int r = 0; r < 4; ++r) {
        int qq = mi * 16 + g4 * 4 + r;
        float denom = rsl[wr][0][qq] + rsl[wr][1][qq];
        float o = oacc[mi][ni][r] / denom;
        int d = wc * 32 + ni * 16 + row16;
        int qc = wr * 32 + qq;
        asm_[APOFF + d * 64 + (((qc >> 3) ^ (d & 7)) * 8 + (qc & 7))] = f2bf(o);
      }
  __syncthreads();
#pragma unroll
  for (int i = 0; i < 2; ++i) {
    int idx = tid + i * 256;
    int r = idx >> 3, c = idx & 7;
    size_t dst = ((size_t)b * DM_ + h * 64 + r) * (2 * FEA_) + br * 512 + q0 + c * 8;
    *(uint4*)(ctx + dst) = *(const uint4*)&asm_[APOFF + r * 64 + ((c ^ (r & 7)) * 8)];
  }
}

// ---------------- LayerNorm over last axis, vectorized ----------------
template <int RESID>
__global__ void ln_kernel(const u16* __restrict__ in, const float* __restrict__ g,
                          const float* __restrict__ beta, const float* __restrict__ resid,
                          void* __restrict__ outp, int C) {
  int row = blockIdx.x;
  int tid = threadIdx.x;
  const u16* p = in + (size_t)row * C;
  float s = 0.f, ss = 0.f;
  for (int c = tid * 4; c < C; c += 1024) {
    ushort4 u = *(const ushort4*)(p + c);
    float v0 = bf2f(u.x), v1 = bf2f(u.y), v2 = bf2f(u.z), v3 = bf2f(u.w);
    s += v0 + v1 + v2 + v3;
    ss += v0 * v0 + v1 * v1 + v2 * v2 + v3 * v3;
  }
#pragma unroll
  for (int m = 1; m < 64; m <<= 1) { s += __shfl_xor(s, m); ss += __shfl_xor(ss, m); }
  __shared__ float red[2][4];
  int wid = tid >> 6, lane = tid & 63;
  if (lane == 0) { red[0][wid] = s; red[1][wid] = ss; }
  __syncthreads();
  s  = red[0][0] + red[0][1] + red[0][2] + red[0][3];
  ss = red[1][0] + red[1][1] + red[1][2] + red[1][3];
  float m  = s / C;
  float var = ss / C - m * m;
  float inv = rsqrtf(var + 1e-5f);
  for (int c = tid * 4; c < C; c += 1024) {
    ushort4 u = *(const ushort4*)(p + c);
    float4 gg = *(const float4*)(g + c);
    float4 bb = *(const float4*)(beta + c);
    float v0 = (bf2f(u.x) - m) * inv * gg.x + bb.x;
    float v1 = (bf2f(u.y) - m) * inv * gg.y + bb.y;
    float v2 = (bf2f(u.z) - m) * inv * gg.z + bb.z;
    float v3 = (bf2f(u.w) - m) * inv * gg.w + bb.w;
    if (RESID) {
      float4 rr = *(const float4*)(resid + (size_t)row * C + c);
      float4 o = {v0 + rr.x, v1 + rr.y, v2 + rr.z, v3 + rr.w};
      *(float4*)((float*)outp + (size_t)row * C + c) = o;
    } else {
      ushort4 o = {f2bf(v0), f2bf(v1), f2bf(v2), f2bf(v3)};
      *(ushort4*)((u16*)outp + (size_t)row * C + c) = o;
    }
  }
}

extern "C" void kernel_launch(void* const* d_in, const int* in_sizes, int n_in,
                              void* d_out, int out_size, void* d_ws, size_t ws_size,
                              hipStream_t stream) {
  (void)in_sizes; (void)n_in; (void)out_size; (void)ws_size;
  const float* x      = (const float*)d_in[0];
  const float* Wq     = (const float*)d_in[1];
  const float* bq     = (const float*)d_in[2];
  const float* Wk     = (const float*)d_in[3];
  const float* bk     = (const float*)d_in[4];
  const float* Wv     = (const float*)d_in[5];
  const float* bv     = (const float*)d_in[6];
  const float* uns_w  = (const float*)d_in[7];
  const float* uns_b  = (const float*)d_in[8];
  const float* cv_w1  = (const float*)d_in[9];
  const float* cv_b1  = (const float*)d_in[10];
  const float* cv_w2  = (const float*)d_in[11];
  const float* cv_b2  = (const float*)d_in[12];
  const float* cv_g   = (const float*)d_in[13];
  const float* cv_beta= (const float*)d_in[14];
  const float* up_w1  = (const float*)d_in[15];
  const float* up_b1  = (const float*)d_in[16];
  const float* up_w2  = (const float*)d_in[17];
  const float* up_b2  = (const float*)d_in[18];
  const float* up_g   = (const float*)d_in[19];
  const float* up_beta= (const float*)d_in[20];

  char* ws = (char*)d_ws;
  const size_t MB = 1ull << 20;
  u16* x1    = (u16*)(ws + 0);
  u16* x1x2  = x1;
  u16* qhb   = (u16*)(ws + 16 * MB);
  u16* khb   = (u16*)(ws + 48 * MB);
  u16* vhb   = (u16*)(ws + 80 * MB);
  u16* qlb   = (u16*)(ws + 32 * MB);
  u16* klb   = (u16*)(ws + 64 * MB);
  u16* vlb   = (u16*)(ws + 96 * MB);
  u16* wt_proj = (u16*)d_out;
  u16* ctx   = (u16*)d_out;
  u16* wt_uns  = (u16*)(ws + 0);
  u16* wt_cv1  = (u16*)(ws + 4 * MB);
  u16* wt_cv2  = (u16*)(ws + 17 * MB);
  u16* wt_up1  = (u16*)(ws + 24 * MB);
  u16* wt_up2  = (u16*)(ws + 31 * MB);
  u16* ctx2  = (u16*)(ws + 48 * MB);
  u16* h1    = (u16*)(ws + 64 * MB);
  u16* h2    = (u16*)(ws + 96 * MB);
  u16* ctx3  = (u16*)(ws + 104 * MB);
  u16* h3    = (u16*)(ws + 64 * MB);
  u16* h4    = (u16*)(ws + 48 * MB);

  dwt_kernel<<<(B_ * FEA_ * HALF_ / 2 + 255) / 256, 256, 0, stream>>>(
      x, x1, (u16*)(ws + 8 * MB), B_ * FEA_ * HALF_ / 2);

  const int NPROJ = DM_ * HALF_ * 3;
  wtrans3_kernel<<<(3 * NPROJ + 255) / 256, 256, 0, stream>>>(Wq, Wk, Wv, wt_proj, DM_, HALF_);

  auto conv = [&](const u16* Z, const u16* wt, const float* bias, u16* out, int L,
                  int Cin, int Cout, int osl, int osc, int relu, int nb) {
    conv_mfma_kernel<<<dim3(L / 128, Cout / 128, nb), 256, 0, stream>>>(
        Z, wt, bias, out, L, Cin, Cout, osl, osc, relu);
  };

  conv(x1x2, wt_proj,              bq, qhb, FEA_, HALF_, DM_, DM_, 1, 0, 32);
  conv(x1x2, wt_proj + NPROJ,      bk, khb, FEA_, HALF_, DM_, DM_, 1, 0, 32);
  conv(x1x2, wt_proj + 2 * NPROJ,  bv, vhb, FEA_, HALF_, DM_, 1, FEA_, 0, 32);

  attn_mfma_kernel<<<dim3(8, 16, 32), 256, 0, stream>>>(qhb, khb, vhb, qlb, klb, vlb, ctx);

  WT5 p;
  int base = 0;
  auto seg = [&](int i, const float* src, u16* dst, int cout, int cin) {
    p.s[i] = {src, dst, cout, cin, base};
    base += cout * cin * 3;
  };
  seg(0, uns_w, wt_uns, FEA_, 2 * FEA_);
  seg(1, cv_w1, wt_cv1, DFF_, DM_);
  seg(2, cv_w2, wt_cv2, HALF_, DFF_);
  seg(3, up_w1, wt_up1, DFF_, HALF_);
  seg(4, up_w2, wt_up2, DM_, DFF_);
  p.total = base;
  wtrans5_kernel<<<(p.total + 255) / 256, 256, 0, stream>>>(p);

  conv(ctx, wt_uns, uns_b, ctx2, DM_, 2 * FEA_, FEA_, 1, DM_, 0, B_);

  conv(ctx2, wt_cv1, cv_b1, h1, FEA_, DM_, DFF_, DFF_, 1, 1, B_);
  conv(h1, wt_cv2, cv_b2, h2, FEA_, DFF_, HALF_, HALF_, 1, 0, B_);
  ln_kernel<0><<<B_ * FEA_, 256, 0, stream>>>(h2, cv_g, cv_beta, nullptr, ctx3, HALF_);

  conv(ctx3, wt_up1, up_b1, h3, FEA_, HALF_, DFF_, DFF_, 1, 1, B_);
  conv(h3, wt_up2, up_b2, h4, FEA_, DFF_, DM_, DM_, 1, 0, B_);
  ln_kernel<1><<<B_ * FEA_, 256, 0, stream>>>(h4, up_g, up_beta, x, d_out, DM_);
}

// Round 21
// 658.633 us; speedup vs baseline: 1.2164x; 1.2164x over previous
//
#include <hip/hip_runtime.h>
#include <hip/hip_bf16.h>

#define B_    16
#define FEA_  512
#define DM_   1024
#define HALF_ 512
#define DFF_  2048

typedef unsigned short u16;
typedef __attribute__((ext_vector_type(8))) short bf16x8;
typedef __attribute__((ext_vector_type(4))) float f32x4;

__device__ __forceinline__ float bf2f(u16 u) {
  union { unsigned int i; float f; } v; v.i = ((unsigned int)u) << 16; return v.f;
}
__device__ __forceinline__ u16 f2bf(float f) {
  union { float f; unsigned int i; } v; v.f = f;
  unsigned int x = v.i;
  return (u16)((x + 0x7fffu + ((x >> 16) & 1u)) >> 16);
}
__device__ __forceinline__ void gload16(const u16* g, u16* l) {
  __builtin_amdgcn_global_load_lds(
      (const __attribute__((address_space(1))) void*)g,
      (__attribute__((address_space(3))) void*)l, 16, 0, 0);
}

// ---------------- DWT (Haar, level 1, last axis), float4 ----------------
__global__ void dwt_kernel(const float* __restrict__ x, u16* __restrict__ x1,
                           u16* __restrict__ x2, int n2) {
  int i = blockIdx.x * 256 + threadIdx.x;
  if (i >= n2) return;
  float4 v = ((const float4*)x)[i];
  ushort2 a, d;
  a.x = f2bf((v.x + v.y) * 0.70710678118f);
  a.y = f2bf((v.z + v.w) * 0.70710678118f);
  d.x = f2bf((v.x - v.y) * 0.70710678118f);
  d.y = f2bf((v.z - v.w) * 0.70710678118f);
  ((ushort2*)x1)[i] = a;
  ((ushort2*)x2)[i] = d;
}

// ---------------- weight transpose, fused variants ----------------
__global__ void wtrans3_kernel(const float* __restrict__ w0, const float* __restrict__ w1,
                               const float* __restrict__ w2, u16* __restrict__ wt,
                               int Cout, int Cin) {
  int n = Cout * Cin * 3;
  int e = blockIdx.x * 256 + threadIdx.x;
  if (e >= 3 * n) return;
  int i = e / n, le = e - i * n;
  const float* w = (i == 0) ? w0 : ((i == 1) ? w1 : w2);
  int co = le / (Cin * 3);
  int r  = le - co * Cin * 3;
  int ci = r / 3;
  int t  = r - ci * 3;
  wt[(size_t)i * n + ((size_t)t * Cout + co) * Cin + ci] = f2bf(w[le]);
}

struct WTSeg { const float* src; u16* dst; int cout, cin, base; };
struct WT5 { WTSeg s[5]; int total; };
__global__ void wtrans5_kernel(WT5 p) {
  int e = blockIdx.x * 256 + threadIdx.x;
  if (e >= p.total) return;
#pragma unroll
  for (int i = 0; i < 5; ++i) {
    int Cin = p.s[i].cin, Cout = p.s[i].cout;
    int n = Cout * Cin * 3;
    int le = e - p.s[i].base;
    if (le >= 0 && le < n) {
      int co = le / (Cin * 3);
      int r  = le - co * Cin * 3;
      int ci = r / 3;
      int t  = r - ci * 3;
      p.s[i].dst[((size_t)t * Cout + co) * Cin + ci] = f2bf(p.s[i].src[le]);
    }
  }
}

// ---------------- circular conv1d (k=3) as MFMA GEMM (r15/r19, 3-buffer) ----------------
#define ZS_GLOAD(c0_)                                                        \
  {                                                                          \
    _Pragma("unroll") for (int i_ = 0; i_ < 5; ++i_) {                       \
      int e_ = tid + i_ * 256;                                               \
      if (e_ < 130 * 8) {                                                    \
        int r_ = e_ >> 3, c_ = e_ & 7;                                       \
        int gl_ = l0 + r_ - 1;                                               \
        if (gl_ < 0) gl_ += L; else if (gl_ >= L) gl_ -= L;                  \
        gload16(Zb + (size_t)gl_ * Cin + (c0_) + ((c_ ^ (r_ & 7)) * 8),      \
                smem + ((size_t)(i_ * 256 + (tid & 192)) * 8));              \
      }                                                                      \
    }                                                                        \
  }
#define WS_ISSUE(t_, c0_, buf_)                                              \
  {                                                                          \
    const u16* Wg_ = Wt + ((size_t)(t_) * Cout + co0) * Cin + (c0_);         \
    int c_ = lane & 7;                                                       \
    _Pragma("unroll") for (int i_ = 0; i_ < 4; ++i_) {                       \
      int rw_ = (i_ * 4 + w) * 8 + (lane >> 3);                              \
      gload16(Wg_ + (size_t)rw_ * Cin + ((c_ ^ (rw_ & 7)) * 8),              \
              &Wb[(buf_)][(i_ * 4 + w) * 8][0]);                             \
    }                                                                        \
  }
#define COMPUTE(t_, buf_)                                                    \
  {                                                                          \
    _Pragma("unroll") for (int ks = 0; ks < 2; ++ks) {                       \
      int s = ks * 4 + g4;                                                   \
      bf16x8 af[4], bfr[4];                                                  \
      _Pragma("unroll") for (int mi = 0; mi < 4; ++mi) {                     \
        int ra = wr * 64 + mi * 16 + row16 + (t_);                           \
        af[mi] = *(const bf16x8*)&Zs[ra][(s ^ (ra & 7)) * 8];                \
      }                                                                      \
      _Pragma("unroll") for (int ni = 0; ni < 4; ++ni) {                     \
        int rb = wc * 64 + ni * 16 + row16;                                  \
        bfr[ni] = *(const bf16x8*)&Wb[(buf_)][rb][(s ^ (rb & 7)) * 8];       \
      }                                                                      \
      __builtin_amdgcn_s_setprio(1);                                         \
      _Pragma("unroll") for (int mi = 0; mi < 4; ++mi)                       \
        _Pragma("unroll") for (int ni = 0; ni < 4; ++ni)                     \
          acc[mi][ni] = __builtin_amdgcn_mfma_f32_16x16x32_bf16(             \
              af[mi], bfr[ni], acc[mi][ni], 0, 0, 0);                        \
      __builtin_amdgcn_s_setprio(0);                                         \
    }                                                                        \
  }
#define COMPUTE2_REG(buf_)                                                   \
  {                                                                          \
    _Pragma("unroll") for (int ks = 0; ks < 2; ++ks) {                       \
      int s = ks * 4 + g4;                                                   \
      bf16x8 bfr[4];                                                         \
      _Pragma("unroll") for (int ni = 0; ni < 4; ++ni) {                     \
        int rb = wc * 64 + ni * 16 + row16;                                  \
        bfr[ni] = *(const bf16x8*)&Wb[(buf_)][rb][(s ^ (rb & 7)) * 8];       \
      }                                                                      \
      __builtin_amdgcn_s_setprio(1);                                         \
      _Pragma("unroll") for (int mi = 0; mi < 4; ++mi)                       \
        _Pragma("unroll") for (int ni = 0; ni < 4; ++ni)                     \
          acc[mi][ni] = __builtin_amdgcn_mfma_f32_16x16x32_bf16(             \
              af2[ks * 4 + mi], bfr[ni], acc[mi][ni], 0, 0, 0);              \
      __builtin_amdgcn_s_setprio(0);                                         \
    }                                                                        \
  }
#define WAIT4 { asm volatile("s_waitcnt vmcnt(4)" ::: "memory");             \
                __builtin_amdgcn_s_barrier(); }

__global__ __launch_bounds__(256, 2) void conv_mfma_kernel(
    const u16* __restrict__ Z, const u16* __restrict__ Wt,
    const float* __restrict__ bias, u16* __restrict__ out,
    int L, int Cin, int Cout, int osl, int osc, int relu) {
  __shared__ __align__(16) u16 smem[130 * 64 + 3 * 128 * 64];
  u16 (*Zs)[64] = (u16(*)[64])smem;
  u16 (*Wb)[128][64] = (u16(*)[128][64])(smem + 130 * 64);
  int l0 = blockIdx.x * 128, co0 = blockIdx.y * 128, b = blockIdx.z;
  int tid = threadIdx.x;
  int lane = tid & 63, w = tid >> 6, wr = w >> 1, wc = w & 1;
  int row16 = lane & 15, g4 = lane >> 4;
  f32x4 acc[4][4];
#pragma unroll
  for (int i = 0; i < 4; ++i)
#pragma unroll
    for (int j = 0; j < 4; ++j) acc[i][j] = (f32x4){0.f, 0.f, 0.f, 0.f};
  const u16* Zb = Z + (size_t)b * L * Cin;

  int ncg = Cin >> 6;
  ZS_GLOAD(0);
  WS_ISSUE(0, 0, 0);
  WS_ISSUE(1, 0, 1);

  for (int cg = 0; cg < ncg; ++cg) {
    int c0 = cg << 6;
    bool lastg = (cg == ncg - 1);
    WAIT4;
    WS_ISSUE(2, c0, 2);
    COMPUTE(0, 0);
    WAIT4;
    if (!lastg) WS_ISSUE(0, c0 + 64, 0);
    COMPUTE(1, 1);
    if (!lastg) {
      WAIT4;
      bf16x8 af2[8];
#pragma unroll
      for (int ks = 0; ks < 2; ++ks) {
        int s = ks * 4 + g4;
#pragma unroll
        for (int mi = 0; mi < 4; ++mi) {
          int ra = wr * 64 + mi * 16 + row16 + 2;
          af2[ks * 4 + mi] = *(const bf16x8*)&Zs[ra][(s ^ (ra & 7)) * 8];
        }
      }
      __builtin_amdgcn_sched_barrier(0);
      asm volatile("s_waitcnt lgkmcnt(0)" ::: "memory");
      __builtin_amdgcn_s_barrier();
      ZS_GLOAD(c0 + 64);
      WS_ISSUE(1, c0 + 64, 1);
      COMPUTE2_REG(2);
    } else {
      asm volatile("s_waitcnt vmcnt(0)" ::: "memory");
      __builtin_amdgcn_s_barrier();
      COMPUTE(2, 2);
    }
  }

  __syncthreads();
  const int TP = 136;
  u16* tile = smem;
  size_t ob = (size_t)b * L * Cout;
  int S, rowbase, colbase;
  if (osc == 1) { S = osl; rowbase = l0; colbase = co0; }
  else          { S = osc; rowbase = co0; colbase = l0; }
#pragma unroll
  for (int ni = 0; ni < 4; ++ni) {
    int c_loc = wc * 64 + ni * 16 + row16;
    float bz = bias[co0 + c_loc];
#pragma unroll
    for (int mi = 0; mi < 4; ++mi) {
#pragma unroll
      for (int r = 0; r < 4; ++r) {
        int l_loc = wr * 64 + mi * 16 + g4 * 4 + r;
        float v = acc[mi][ni][r] + bz;
        if (relu) v = fmaxf(v, 0.f);
        int row = (osc == 1) ? l_loc : c_loc;
        int col = (osc == 1) ? c_loc : l_loc;
        tile[row * TP + col] = f2bf(v);
      }
    }
  }
  __syncthreads();
  for (int e = tid; e < 128 * 16; e += 256) {
    int row = e >> 4, c8 = (e & 15) * 8;
    *(uint4*)(out + ob + (size_t)(rowbase + row) * S + colbase + c8) =
        *(const uint4*)&tile[row * TP + c8];
  }
}

// ---------------- fused cross attention, MFMA, pipelined (r17) ----------------
#define AQOFF 0
#define AKOFF 4096
#define AVOFF 12288
#define APOFF 20480
#define AT_Q_STAGE()                                                         \
  { _Pragma("unroll") for (int i_ = 0; i_ < 2; ++i_) {                       \
      int idx_ = tid + i_ * 256; int r_ = idx_ >> 3, c_ = idx_ & 7;          \
      gload16(Qg + (size_t)(q0 + r_) * DM_ + ((c_ ^ (r_ & 7)) * 8),          \
              asm_ + AQOFF + (i_ * 256 + (tid & 192)) * 8); } }
#define AT_K_STAGE(kt_, buf_)                                                \
  { _Pragma("unroll") for (int i_ = 0; i_ < 2; ++i_) {                       \
      int idx_ = tid + i_ * 256; int r_ = idx_ >> 3, c_ = idx_ & 7;          \
      gload16(Kg + (size_t)((kt_) * 64 + r_) * DM_ + ((c_ ^ (r_ & 7)) * 8),  \
              asm_ + AKOFF + (buf_) * 4096 + (i_ * 256 + (tid & 192)) * 8); } }
#define AT_V_STAGE(kt_, buf_)                                                \
  { _Pragma("unroll") for (int i_ = 0; i_ < 2; ++i_) {                       \
      int idx_ = tid + i_ * 256; int r_ = idx_ >> 3, c_ = idx_ & 7;          \
      gload16(Vg + (size_t)r_ * FEA_ + (kt_) * 64 + ((c_ ^ (r_ & 7)) * 8),   \
              asm_ + AVOFF + (buf_) * 4096 + (i_ * 256 + (tid & 192)) * 8); } }
#define LGKM0_BAR { asm volatile("s_waitcnt lgkmcnt(0)" ::: "memory");       \
                    __builtin_amdgcn_s_barrier(); }

__global__ __launch_bounds__(256, 3) void attn_mfma_kernel(
    const u16* __restrict__ qh, const u16* __restrict__ kh, const u16* __restrict__ vhT,
    const u16* __restrict__ ql, const u16* __restrict__ kl, const u16* __restrict__ vlT,
    u16* __restrict__ ctx) {
  __shared__ __align__(16) u16 asm_[24576];
  __shared__ float rsl[2][2][32];   // [wr][wc][q]
  int qt = blockIdx.x, h = blockIdx.y, bz = blockIdx.z;
  int b = bz >> 1, br = bz & 1;
  const u16* Qg = (br ? ql  : qh) + (size_t)b * FEA_ * DM_ + h * 64;
  const u16* Kg = (br ? kh  : kl) + (size_t)b * FEA_ * DM_ + h * 64;
  const u16* Vg = (br ? vlT : vhT) + (size_t)b * DM_ * FEA_ + (size_t)(h * 64) * FEA_;
  int tid = threadIdx.x;
  int lane = tid & 63, w = tid >> 6, wr = w >> 1, wc = w & 1;
  int row16 = lane & 15, g4 = lane >> 4;
  int q0 = qt * 64;

  f32x4 oacc[2][2];
  float rsum[2][4];
#pragma unroll
  for (int i = 0; i < 2; ++i) {
#pragma unroll
    for (int j = 0; j < 2; ++j) oacc[i][j] = (f32x4){0.f, 0.f, 0.f, 0.f};
#pragma unroll
    for (int r = 0; r < 4; ++r) rsum[i][r] = 0.f;
  }

  AT_Q_STAGE();
  AT_K_STAGE(0, 0); AT_V_STAGE(0, 0);

  for (int kt = 0; kt < 8; ++kt) {
    int buf = kt & 1;
    asm volatile("s_waitcnt vmcnt(0)" ::: "memory");
    __builtin_amdgcn_s_barrier();
    if (kt < 7) { AT_K_STAGE(kt + 1, buf ^ 1); AT_V_STAGE(kt + 1, buf ^ 1); }
    f32x4 sacc[2][2];
#pragma unroll
    for (int i = 0; i < 2; ++i)
#pragma unroll
      for (int j = 0; j < 2; ++j) sacc[i][j] = (f32x4){0.f, 0.f, 0.f, 0.f};
#pragma unroll
    for (int ks = 0; ks < 2; ++ks) {
      int s = ks * 4 + g4;
      bf16x8 a0, a1, b0, b1;
      { int ra = wr * 32 + row16;
        a0 = *(const bf16x8*)&asm_[AQOFF + ra * 64 + ((s ^ (ra & 7)) * 8)]; }
      { int ra = wr * 32 + 16 + row16;
        a1 = *(const bf16x8*)&asm_[AQOFF + ra * 64 + ((s ^ (ra & 7)) * 8)]; }
      { int rb = wc * 32 + row16;
        b0 = *(const bf16x8*)&asm_[AKOFF + buf * 4096 + rb * 64 + ((s ^ (rb & 7)) * 8)]; }
      { int rb = wc * 32 + 16 + row16;
        b1 = *(const bf16x8*)&asm_[AKOFF + buf * 4096 + rb * 64 + ((s ^ (rb & 7)) * 8)]; }
      __builtin_amdgcn_s_setprio(1);
      sacc[0][0] = __builtin_amdgcn_mfma_f32_16x16x32_bf16(a0, b0, sacc[0][0], 0, 0, 0);
      sacc[0][1] = __builtin_amdgcn_mfma_f32_16x16x32_bf16(a0, b1, sacc[0][1], 0, 0, 0);
      sacc[1][0] = __builtin_amdgcn_mfma_f32_16x16x32_bf16(a1, b0, sacc[1][0], 0, 0, 0);
      sacc[1][1] = __builtin_amdgcn_mfma_f32_16x16x32_bf16(a1, b1, sacc[1][1], 0, 0, 0);
      __builtin_amdgcn_s_setprio(0);
    }
#pragma unroll
    for (int mi = 0; mi < 2; ++mi)
#pragma unroll
      for (int ni = 0; ni < 2; ++ni)
#pragma unroll
        for (int r = 0; r < 4; ++r) {
          float p = __expf(sacc[mi][ni][r] * 0.25f);
          rsum[mi][r] += p;
          int pr = wr * 32 + mi * 16 + g4 * 4 + r;
          int ck = wc * 32 + ni * 16 + row16;
          asm_[APOFF + pr * 64 + (((ck >> 3) ^ (pr & 7)) * 8 + (ck & 7))] = f2bf(p);
        }
    LGKM0_BAR;                    // Ps published
#pragma unroll
    for (int ks = 0; ks < 2; ++ks) {
      int s = ks * 4 + g4;
      bf16x8 a0, a1, b0, b1;
      { int pa = wr * 32 + row16;
        a0 = *(const bf16x8*)&asm_[APOFF + pa * 64 + ((s ^ (pa & 7)) * 8)]; }
      { int pa = wr * 32 + 16 + row16;
        a1 = *(const bf16x8*)&asm_[APOFF + pa * 64 + ((s ^ (pa & 7)) * 8)]; }
      { int rv = wc * 32 + row16;
        b0 = *(const bf16x8*)&asm_[AVOFF + buf * 4096 + rv * 64 + ((s ^ (rv & 7)) * 8)]; }
      { int rv = wc * 32 + 16 + row16;
        b1 = *(const bf16x8*)&asm_[AVOFF + buf * 4096 + rv * 64 + ((s ^ (rv & 7)) * 8)]; }
      __builtin_amdgcn_s_setprio(1);
      oacc[0][0] = __builtin_amdgcn_mfma_f32_16x16x32_bf16(a0, b0, oacc[0][0], 0, 0, 0);
      oacc[0][1] = __builtin_amdgcn_mfma_f32_16x16x32_bf16(a0, b1, oacc[0][1], 0, 0, 0);
      oacc[1][0] = __builtin_amdgcn_mfma_f32_16x16x32_bf16(a1, b0, oacc[1][0], 0, 0, 0);
      oacc[1][1] = __builtin_amdgcn_mfma_f32_16x16x32_bf16(a1, b1, oacc[1][1], 0, 0, 0);
      __builtin_amdgcn_s_setprio(0);
    }
  }

  // ---- epilogue: denominators, O staging (reuse P area as Ot[d][q]), write ----
#pragma unroll
  for (int mi = 0; mi < 2; ++mi)
#pragma unroll
    for (int r = 0; r < 4; ++r) {
#pragma unroll
      for (int m = 1; m < 16; m <<= 1) rsum[mi][r] += __shfl_xor(rsum[mi][r], m);
    }
  if (row16 == 0) {
#pragma unroll
    for (int mi = 0; mi < 2; ++mi)
#pragma unroll
      for (int r = 0; r < 4; ++r) rsl[wr][wc][mi * 16 + g4 * 4 + r] = rsum[mi][r];
  }
  __syncthreads();
#pragma unroll
  for (int mi = 0; mi < 2; ++mi)
#pragma unroll
    for (int ni = 0; ni < 2; ++ni)
#pragma unroll
      for (int r = 0; r < 4; ++r) {
        int qq = mi * 16 + g4 * 4 + r;
        float denom = rsl[wr][0][qq] + rsl[wr][1][qq];
        float o = oacc[mi][ni][r] / denom;
        int d = wc * 32 + ni * 16 + row16;
        int qc = wr * 32 + qq;
        asm_[APOFF + d * 64 + (((qc >> 3) ^ (d & 7)) * 8 + (qc & 7))] = f2bf(o);
      }
  __syncthreads();
#pragma unroll
  for (int i = 0; i < 2; ++i) {
    int idx = tid + i * 256;
    int r = idx >> 3, c = idx & 7;
    size_t dst = ((size_t)b * DM_ + h * 64 + r) * (2 * FEA_) + br * 512 + q0 + c * 8;
    *(uint4*)(ctx + dst) = *(const uint4*)&asm_[APOFF + r * 64 + ((c ^ (r & 7)) * 8)];
  }
}

// ---------------- LayerNorm over last axis, vectorized ----------------
template <int RESID>
__global__ void ln_kernel(const u16* __restrict__ in, const float* __restrict__ g,
                          const float* __restrict__ beta, const float* __restrict__ resid,
                          void* __restrict__ outp, int C) {
  int row = blockIdx.x;
  int tid = threadIdx.x;
  const u16* p = in + (size_t)row * C;
  float s = 0.f, ss = 0.f;
  for (int c = tid * 4; c < C; c += 1024) {
    ushort4 u = *(const ushort4*)(p + c);
    float v0 = bf2f(u.x), v1 = bf2f(u.y), v2 = bf2f(u.z), v3 = bf2f(u.w);
    s += v0 + v1 + v2 + v3;
    ss += v0 * v0 + v1 * v1 + v2 * v2 + v3 * v3;
  }
#pragma unroll
  for (int m = 1; m < 64; m <<= 1) { s += __shfl_xor(s, m); ss += __shfl_xor(ss, m); }
  __shared__ float red[2][4];
  int wid = tid >> 6, lane = tid & 63;
  if (lane == 0) { red[0][wid] = s; red[1][wid] = ss; }
  __syncthreads();
  s  = red[0][0] + red[0][1] + red[0][2] + red[0][3];
  ss = red[1][0] + red[1][1] + red[1][2] + red[1][3];
  float m  = s / C;
  float var = ss / C - m * m;
  float inv = rsqrtf(var + 1e-5f);
  for (int c = tid * 4; c < C; c += 1024) {
    ushort4 u = *(const ushort4*)(p + c);
    float4 gg = *(const float4*)(g + c);
    float4 bb = *(const float4*)(beta + c);
    float v0 = (bf2f(u.x) - m) * inv * gg.x + bb.x;
    float v1 = (bf2f(u.y) - m) * inv * gg.y + bb.y;
    float v2 = (bf2f(u.z) - m) * inv * gg.z + bb.z;
    float v3 = (bf2f(u.w) - m) * inv * gg.w + bb.w;
    if (RESID) {
      float4 rr = *(const float4*)(resid + (size_t)row * C + c);
      float4 o = {v0 + rr.x, v1 + rr.y, v2 + rr.z, v3 + rr.w};
      *(float4*)((float*)outp + (size_t)row * C + c) = o;
    } else {
      ushort4 o = {f2bf(v0), f2bf(v1), f2bf(v2), f2bf(v3)};
      *(ushort4*)((u16*)outp + (size_t)row * C + c) = o;
    }
  }
}

extern "C" void kernel_launch(void* const* d_in, const int* in_sizes, int n_in,
                              void* d_out, int out_size, void* d_ws, size_t ws_size,
                              hipStream_t stream) {
  (void)in_sizes; (void)n_in; (void)out_size; (void)ws_size;
  const float* x      = (const float*)d_in[0];
  const float* Wq     = (const float*)d_in[1];
  const float* bq     = (const float*)d_in[2];
  const float* Wk     = (const float*)d_in[3];
  const float* bk     = (const float*)d_in[4];
  const float* Wv     = (const float*)d_in[5];
  const float* bv     = (const float*)d_in[6];
  const float* uns_w  = (const float*)d_in[7];
  const float* uns_b  = (const float*)d_in[8];
  const float* cv_w1  = (const float*)d_in[9];
  const float* cv_b1  = (const float*)d_in[10];
  const float* cv_w2  = (const float*)d_in[11];
  const float* cv_b2  = (const float*)d_in[12];
  const float* cv_g   = (const float*)d_in[13];
  const float* cv_beta= (const float*)d_in[14];
  const float* up_w1  = (const float*)d_in[15];
  const float* up_b1  = (const float*)d_in[16];
  const float* up_w2  = (const float*)d_in[17];
  const float* up_b2  = (const float*)d_in[18];
  const float* up_g   = (const float*)d_in[19];
  const float* up_beta= (const float*)d_in[20];

  char* ws = (char*)d_ws;
  const size_t MB = 1ull << 20;
  u16* x1    = (u16*)(ws + 0);
  u16* x1x2  = x1;
  u16* qhb   = (u16*)(ws + 16 * MB);
  u16* khb   = (u16*)(ws + 48 * MB);
  u16* vhb   = (u16*)(ws + 80 * MB);
  u16* qlb   = (u16*)(ws + 32 * MB);
  u16* klb   = (u16*)(ws + 64 * MB);
  u16* vlb   = (u16*)(ws + 96 * MB);
  u16* wt_proj = (u16*)d_out;
  u16* ctx   = (u16*)d_out;
  u16* wt_uns  = (u16*)(ws + 0);
  u16* wt_cv1  = (u16*)(ws + 4 * MB);
  u16* wt_cv2  = (u16*)(ws + 17 * MB);
  u16* wt_up1  = (u16*)(ws + 24 * MB);
  u16* wt_up2  = (u16*)(ws + 31 * MB);
  u16* ctx2  = (u16*)(ws + 48 * MB);
  u16* h1    = (u16*)(ws + 64 * MB);
  u16* h2    = (u16*)(ws + 96 * MB);
  u16* ctx3  = (u16*)(ws + 104 * MB);
  u16* h3    = (u16*)(ws + 64 * MB);
  u16* h4    = (u16*)(ws + 48 * MB);

  dwt_kernel<<<(B_ * FEA_ * HALF_ / 2 + 255) / 256, 256, 0, stream>>>(
      x, x1, (u16*)(ws + 8 * MB), B_ * FEA_ * HALF_ / 2);

  const int NPROJ = DM_ * HALF_ * 3;
  wtrans3_kernel<<<(3 * NPROJ + 255) / 256, 256, 0, stream>>>(Wq, Wk, Wv, wt_proj, DM_, HALF_);

  auto conv = [&](const u16* Z, const u16* wt, const float* bias, u16* out, int L,
                  int Cin, int Cout, int osl, int osc, int relu, int nb) {
    conv_mfma_kernel<<<dim3(L / 128, Cout / 128, nb), 256, 0, stream>>>(
        Z, wt, bias, out, L, Cin, Cout, osl, osc, relu);
  };

  conv(x1x2, wt_proj,              bq, qhb, FEA_, HALF_, DM_, DM_, 1, 0, 32);
  conv(x1x2, wt_proj + NPROJ,      bk, khb, FEA_, HALF_, DM_, DM_, 1, 0, 32);
  conv(x1x2, wt_proj + 2 * NPROJ,  bv, vhb, FEA_, HALF_, DM_, 1, FEA_, 0, 32);

  attn_mfma_kernel<<<dim3(8, 16, 32), 256, 0, stream>>>(qhb, khb, vhb, qlb, klb, vlb, ctx);

  WT5 p;
  int base = 0;
  auto seg = [&](int i, const float* src, u16* dst, int cout, int cin) {
    p.s[i] = {src, dst, cout, cin, base};
    base += cout * cin * 3;
  };
  seg(0, uns_w, wt_uns, FEA_, 2 * FEA_);
  seg(1, cv_w1, wt_cv1, DFF_, DM_);
  seg(2, cv_w2, wt_cv2, HALF_, DFF_);
  seg(3, up_w1, wt_up1, DFF_, HALF_);
  seg(4, up_w2, wt_up2, DM_, DFF_);
  p.total = base;
  wtrans5_kernel<<<(p.total + 255) / 256, 256, 0, stream>>>(p);

  conv(ctx, wt_uns, uns_b, ctx2, DM_, 2 * FEA_, FEA_, 1, DM_, 0, B_);

  conv(ctx2, wt_cv1, cv_b1, h1, FEA_, DM_, DFF_, DFF_, 1, 1, B_);
  conv(h1, wt_cv2, cv_b2, h2, FEA_, DFF_, HALF_, HALF_, 1, 0, B_);
  ln_kernel<0><<<B_ * FEA_, 256, 0, stream>>>(h2, cv_g, cv_beta, nullptr, ctx3, HALF_);

  conv(ctx3, wt_up1, up_b1, h3, FEA_, HALF_, DFF_, DFF_, 1, 1, B_);
  conv(h3, wt_up2, up_b2, h4, FEA_, DFF_, DM_, DM_, 1, 0, B_);
  ln_kernel<1><<<B_ * FEA_, 256, 0, stream>>>(h4, up_g, up_beta, x, d_out, DM_);
}